// Round 2
// baseline (845.008 us; speedup 1.0000x reference)
//
#include <hip/hip_runtime.h>

typedef _Float16 half_t;
typedef _Float16 half8  __attribute__((ext_vector_type(8)));
typedef _Float16 half2v __attribute__((ext_vector_type(2)));
typedef float    floatx4 __attribute__((ext_vector_type(4)));

#define MFMA16(a, b, c) __builtin_amdgcn_mfma_f32_16x16x32_f16((a), (b), (c), 0, 0, 0)

// ---------------------------------------------------------------------------
// Merged prep: [blocks 0..4607] fc1 w fp32->fp16; [4608..4679] conv2 w
// transpose->fp16; [4680] GMM Sigma_inv + det_scale.
// ---------------------------------------------------------------------------
__global__ void k_prep(const float* __restrict__ fw1, half_t* __restrict__ W1h,
                       const float* __restrict__ w2, half_t* __restrict__ W2T,
                       const float* __restrict__ raw, float* __restrict__ Sinv,
                       float* __restrict__ dets) {
    const int blk = blockIdx.x;
    const int t = threadIdx.x;
    if (blk < 4608) {
        const int i = blk * 256 + t;  // 1179648 exact
        W1h[i] = (half_t)fw1[i];
    } else if (blk < 4680) {
        const int i = (blk - 4608) * 256 + t;
        if (i < 18432) {
            const int tap = i / 2048;
            const int r = i - tap * 2048;
            const int co = r >> 5;
            const int ci = r & 31;
            W2T[i] = (half_t)w2[(co * 32 + ci) * 9 + tap];
        }
    } else {
        __shared__ float Li[10][10][10];
        if (t < 10) {
            const float* R = raw + t * 100;
            for (int j = 0; j < 10; ++j) {
                for (int i = 0; i < 10; ++i) Li[t][i][j] = (i == j) ? 1.0f : 0.0f;
                for (int i = j + 1; i < 10; ++i) {
                    float s = 0.0f;
                    for (int m = j; m < i; ++m) s -= R[i * 10 + m] * Li[t][m][j];
                    Li[t][i][j] = s;
                }
            }
            float Dl[10];
            float prod = 1.0f;
#pragma unroll
            for (int a = 0; a < 10; ++a) {
                float rd = R[a * 10 + a];
                float dv = rd * rd + 1e-4f;
                Dl[a] = 1.0f / dv;
                prod *= dv;
            }
            dets[t] = rsqrtf(prod);
            for (int i = 0; i < 10; ++i)
                for (int j = 0; j < 10; ++j) {
                    float s = 0.0f;
#pragma unroll
                    for (int a = 0; a < 10; ++a) s += Li[t][a][i] * Dl[a] * Li[t][a][j];
                    Sinv[t * 100 + i * 10 + j] = s;
                }
        }
    }
}

// ---------------------------------------------------------------------------
// Fused conv1(fp32) + conv2(MFMA f16) + bias/ReLU/2x2-maxpool.
// One block per image HALF (hy in {0,1}): LDS 26.6 KB -> 5 blocks/CU resident,
// breaking the conv1(VALU)/conv2(LDS+MFMA) phase convoy seen in round 1.
//   block computes pool rows hy*6..hy*6+5  <- conv2 rows hy*12..+11
//   <- h1 local rows 0..13 (global hy*12..+13) <- x rows hy*12..+15
// h2p layout: [b][co*144 + PY*12 + PX]
// ---------------------------------------------------------------------------
__global__ __launch_bounds__(256, 5) void k_convs(
    const float* __restrict__ x, const float* __restrict__ w1,
    const float* __restrict__ b1, const float* __restrict__ b2,
    const half_t* __restrict__ W2T, half_t* __restrict__ h2p) {
    __shared__ float s_x[448];  // 16 rows x 28
    __shared__ float s_w1[288];
    __shared__ float s_b1[32];
    __shared__ float s_b2[64];
    __shared__ __align__(16) half_t s_h1[4][14][26][8];  // [ci/8][y][x][ci%8]

    const int t = threadIdx.x;
    const int bid = blockIdx.x;
    const int b = bid >> 1;
    const int hy = bid & 1;

    for (int i = t; i < 448; i += 256) s_x[i] = x[(size_t)b * 784 + hy * 336 + i];
    for (int i = t; i < 288; i += 256) s_w1[i] = w1[i];
    if (t < 32) s_b1[t] = b1[t];
    if (t < 64) s_b2[t] = b2[t];
    __syncthreads();

    // ---- conv1: wave g owns ci-group g (8 channels); 364 px (14 rows x 26) ----
    {
        const int g = t >> 6;
        const int u = t & 63;
        float wr[8][9], br[8];
#pragma unroll
        for (int j = 0; j < 8; ++j) {
            br[j] = s_b1[g * 8 + j];
#pragma unroll
            for (int k = 0; k < 9; ++k) wr[j][k] = s_w1[(g * 8 + j) * 9 + k];
        }
        for (int p = u; p < 364; p += 64) {
            const int yy = p / 26;  // local h1 row 0..13
            const int xx = p - yy * 26;
            float win[9];
#pragma unroll
            for (int r = 0; r < 3; ++r)
#pragma unroll
                for (int c = 0; c < 3; ++c) win[r * 3 + c] = s_x[(yy + r) * 28 + xx + c];
            half8 hv;
#pragma unroll
            for (int j = 0; j < 8; ++j) {
                float a = br[j];
#pragma unroll
                for (int k = 0; k < 9; ++k) a = fmaf(win[k], wr[j][k], a);
                hv[j] = (half_t)fmaxf(a, 0.0f);
            }
            *(half8*)(&s_h1[g][yy][xx][0]) = hv;
        }
    }
    __syncthreads();

    // ---- conv2: 18 M-tiles (6ty x 3tx of 2y x 8x), wave-strided ----
    const int w = t >> 6;
    const int ln = t & 63;
    const int n16 = ln & 15;
    const int q = ln >> 4;
    const int dy = (ln >> 3) & 1;  // A-row role: m = ln&15 -> (dy,dx)
    const int dx = ln & 7;

    half8 bf[9][4];  // B-frags: [tap][co-tile]
#pragma unroll
    for (int tap = 0; tap < 9; ++tap)
#pragma unroll
        for (int ct = 0; ct < 4; ++ct)
            bf[tap][ct] = *(const half8*)(W2T + ((tap * 64 + ct * 16 + n16) * 32 + q * 8));

    for (int mt = w; mt < 18; mt += 4) {
        const int ty = mt / 3;       // 0..5 pool row within half
        const int tx = mt - ty * 3;  // 0..2
        const int y0 = 2 * ty;       // local conv2 row base (h1 rows y0..y0+3)
        const int x0 = 8 * tx;
        floatx4 acc[4];
#pragma unroll
        for (int ct = 0; ct < 4; ++ct) acc[ct] = (floatx4){0.f, 0.f, 0.f, 0.f};
#pragma unroll
        for (int tap = 0; tap < 9; ++tap) {
            const int ky = tap / 3;
            const int kx = tap - ky * 3;
            half8 af = *(const half8*)(&s_h1[q][y0 + dy + ky][x0 + dx + kx][0]);
#pragma unroll
            for (int ct = 0; ct < 4; ++ct) acc[ct] = MFMA16(af, bf[tap][ct], acc[ct]);
        }
        // 2x2 maxpool + bias + relu. C row m=q*4+reg; lane^32 is the dy partner.
        const int PY = hy * 6 + ty;
#pragma unroll
        for (int ct = 0; ct < 4; ++ct) {
            float p0 = fmaxf(acc[ct][0], acc[ct][1]);
            float p1 = fmaxf(acc[ct][2], acc[ct][3]);
            p0 = fmaxf(p0, __shfl_xor(p0, 32, 64));
            p1 = fmaxf(p1, __shfl_xor(p1, 32, 64));
            if (q < 2) {
                const int co = ct * 16 + n16;
                const float bb = s_b2[co];
                half2v hz;
                hz[0] = (half_t)fmaxf(p0 + bb, 0.0f);
                hz[1] = (half_t)fmaxf(p1 + bb, 0.0f);
                *(half2v*)(h2p + (size_t)b * 9216 + co * 144 + PY * 12 + 4 * tx + 2 * q) = hz;
            }
        }
    }
}

// ---------------------------------------------------------------------------
// fc1: C[4096,128] = A[4096,9216](fp16) x W^T. Split-K=16 (chunk 576).
// LDS-free, barrier-free: A/B fragments loaded straight from global (A bytes
// read exactly once across the grid; W slice is L2-hot). Grid 32x16 = 512
// blocks = 2/CU. fp16 partials.
// ---------------------------------------------------------------------------
__global__ __launch_bounds__(256) void k_fc1(const half_t* __restrict__ A,
                                             const half_t* __restrict__ W,
                                             half_t* __restrict__ part) {
    const int t = threadIdx.x;
    const int mb = blockIdx.x;  // 0..31
    const int kb = blockIdx.y;  // 0..15
    const int w = t >> 6, ln = t & 63, n16 = ln & 15, q = ln >> 4;

    const half_t* a0 = A + (size_t)(mb * 128 + w * 32 + n16) * 9216 + kb * 576 + q * 8;
    const half_t* a1 = a0 + (size_t)16 * 9216;
    const half_t* wp = W + (size_t)n16 * 9216 + kb * 576 + q * 8;

    floatx4 acc[2][8];
#pragma unroll
    for (int s = 0; s < 2; ++s)
#pragma unroll
        for (int nt = 0; nt < 8; ++nt) acc[s][nt] = (floatx4){0.f, 0.f, 0.f, 0.f};

    for (int kt = 0; kt < 18; ++kt) {
        const int ko = kt * 32;
        half8 af0 = *(const half8*)(a0 + ko);
        half8 af1 = *(const half8*)(a1 + ko);
#pragma unroll
        for (int nt = 0; nt < 8; ++nt) {
            half8 bfr = *(const half8*)(wp + (size_t)nt * 16 * 9216 + ko);
            acc[0][nt] = MFMA16(af0, bfr, acc[0][nt]);
            acc[1][nt] = MFMA16(af1, bfr, acc[1][nt]);
        }
    }
    const int rowbase = mb * 128 + w * 32;
#pragma unroll
    for (int s = 0; s < 2; ++s)
#pragma unroll
        for (int nt = 0; nt < 8; ++nt)
#pragma unroll
            for (int r = 0; r < 4; ++r) {
                const int row = rowbase + s * 16 + q * 4 + r;
                const int col = nt * 16 + n16;
                part[(size_t)kb * 524288 + (size_t)row * 128 + col] = (half_t)acc[s][nt][r];
            }
}

// ---------------------------------------------------------------------------
// fc1 split-K reduction + bias + ReLU -> fp16 h3
// ---------------------------------------------------------------------------
__global__ void k_fc1red(const half_t* __restrict__ part, const float* __restrict__ b,
                         half_t* __restrict__ h3) {
    const int idx = blockIdx.x * 256 + threadIdx.x;  // 524288 exact
    const int col = idx & 127;
    float s = 0.0f;
#pragma unroll
    for (int j = 0; j < 16; ++j) s += (float)part[(size_t)j * 524288 + idx];
    s = fmaxf(s + b[col], 0.0f);
    h3[idx] = (half_t)s;
}

// ---------------------------------------------------------------------------
// fc2 + GMM posterior (fp32). One thread per sample.
// ---------------------------------------------------------------------------
__global__ __launch_bounds__(256) void k_fc2gmm(
    const half_t* __restrict__ h3, const float* __restrict__ fw,
    const float* __restrict__ fb, const float* __restrict__ cent,
    const float* __restrict__ Sinv, const float* __restrict__ dets,
    float* __restrict__ out) {
    __shared__ float sw[1280];
    __shared__ float sb[10];
    __shared__ float sc[100];
    __shared__ float ss[1000];
    __shared__ float sd[10];
    const int t = threadIdx.x;
    for (int i = t; i < 1280; i += 256) sw[i] = fw[i];
    if (t < 10) sb[t] = fb[t];
    if (t < 100) sc[t] = cent[t];
    for (int i = t; i < 1000; i += 256) ss[i] = Sinv[i];
    if (t < 10) sd[t] = dets[t];
    __syncthreads();

    const int bidx = blockIdx.x * 256 + t;  // 4096 samples exact
    half2v hh[64];
    const half2v* hp = (const half2v*)(h3 + (size_t)bidx * 128);
#pragma unroll
    for (int i = 0; i < 64; ++i) hh[i] = hp[i];

    float y[10];
#pragma unroll
    for (int o = 0; o < 10; ++o) {
        float a = sb[o];
#pragma unroll
        for (int k = 0; k < 64; ++k) {
            a = fmaf((float)hh[k][0], sw[o * 128 + 2 * k], a);
            a = fmaf((float)hh[k][1], sw[o * 128 + 2 * k + 1], a);
        }
        y[o] = a;
    }

    float expo[10];
    float mx = -3.402823466e38f;
#pragma unroll
    for (int k = 0; k < 10; ++k) {
        float d[10];
#pragma unroll
        for (int j = 0; j < 10; ++j) d[j] = y[j] - sc[k * 10 + j];
        float s = 0.0f;
#pragma unroll
        for (int i = 0; i < 10; ++i) {
            float r = 0.0f;
#pragma unroll
            for (int j = 0; j < 10; ++j) r = fmaf(ss[k * 100 + i * 10 + j], d[j], r);
            s = fmaf(d[i], r, s);
        }
        expo[k] = -0.5f * s;
        mx = fmaxf(mx, expo[k]);
    }
    float num[10];
    float sum = 0.0f;
#pragma unroll
    for (int k = 0; k < 10; ++k) {
        num[k] = sd[k] * __expf(expo[k] - mx);
        sum += num[k];
    }
    const float inv = 1.0f / sum;
#pragma unroll
    for (int k = 0; k < 10; ++k) out[(size_t)bidx * 10 + k] = num[k] * inv;
}

// ---------------------------------------------------------------------------
extern "C" void kernel_launch(void* const* d_in, const int* in_sizes, int n_in,
                              void* d_out, int out_size, void* d_ws, size_t ws_size,
                              hipStream_t stream) {
    const float* x = (const float*)d_in[0];
    const float* w1 = (const float*)d_in[1];
    const float* b1 = (const float*)d_in[2];
    const float* w2 = (const float*)d_in[3];
    const float* b2 = (const float*)d_in[4];
    const float* fw1 = (const float*)d_in[5];
    const float* fb1 = (const float*)d_in[6];
    const float* fw2 = (const float*)d_in[7];
    const float* fb2 = (const float*)d_in[8];
    const float* cen = (const float*)d_in[9];
    const float* raw = (const float*)d_in[10];
    float* out = (float*)d_out;

    char* ws = (char*)d_ws;
    half_t* W2T = (half_t*)(ws);                 //    36,864 B
    half_t* W1h = (half_t*)(ws + 36864);         // 2,359,296 B
    half_t* h2p = (half_t*)(ws + 2396160);       // 75,497,472 B
    half_t* part = (half_t*)(ws + 77893632);     // 16,777,216 B (16 x 524288 fp16)
    half_t* h3h = (half_t*)(ws + 94670848);      // 1,048,576 B
    float* gS = (float*)(ws + 95719424);         //     4,000 B
    float* gD = (float*)(ws + 95723424);         //        40 B  (total ~95.7 MB)

    k_prep<<<4681, 256, 0, stream>>>(fw1, W1h, w2, W2T, raw, gS, gD);
    k_convs<<<8192, 256, 0, stream>>>(x, w1, b1, b2, W2T, h2p);
    k_fc1<<<dim3(32, 16), 256, 0, stream>>>(h2p, W1h, part);
    k_fc1red<<<2048, 256, 0, stream>>>(part, fb1, h3h);
    k_fc2gmm<<<16, 256, 0, stream>>>(h3h, fw2, fb2, cen, gS, gD, out);
}

// Round 3
// 283.638 us; speedup vs baseline: 2.9792x; 2.9792x over previous
//
#include <hip/hip_runtime.h>

typedef _Float16 half_t;
typedef _Float16 half8  __attribute__((ext_vector_type(8)));
typedef _Float16 half2v __attribute__((ext_vector_type(2)));
typedef float    floatx4 __attribute__((ext_vector_type(4)));

#define MFMA16(a, b, c) __builtin_amdgcn_mfma_f32_16x16x32_f16((a), (b), (c), 0, 0, 0)

// ---------------------------------------------------------------------------
// Merged prep: [blocks 0..4607] fc1 w fp32->fp16; [4608..4679] conv2 w
// transpose->fp16; [4680] GMM Sigma_inv + det_scale (REGISTERIZED: the old
// LDS-based forward substitution was a ~1650-deep chain of ~120cyc LDS reads
// == the hidden ~100us in rounds 1-2).
// ---------------------------------------------------------------------------
__global__ void k_prep(const float* __restrict__ fw1, half_t* __restrict__ W1h,
                       const float* __restrict__ w2, half_t* __restrict__ W2T,
                       const float* __restrict__ raw, float* __restrict__ Sinv,
                       float* __restrict__ dets) {
    const int blk = blockIdx.x;
    const int t = threadIdx.x;
    if (blk < 4608) {
        const int i = blk * 256 + t;  // 1179648 exact
        W1h[i] = (half_t)fw1[i];
    } else if (blk < 4680) {
        const int i = (blk - 4608) * 256 + t;
        if (i < 18432) {
            const int tap = i / 2048;
            const int r = i - tap * 2048;
            const int co = r >> 5;
            const int ci = r & 31;
            W2T[i] = (half_t)w2[(co * 32 + ci) * 9 + tap];
        }
    } else if (t < 10) {
        // thread t owns component t; everything in registers (unrolled)
        const float* R = raw + t * 100;
        float Rr[100];
#pragma unroll
        for (int i = 0; i < 100; ++i) Rr[i] = R[i];
        float Li[10][10];
#pragma unroll
        for (int j = 0; j < 10; ++j) {
#pragma unroll
            for (int i = 0; i < 10; ++i) Li[i][j] = (i == j) ? 1.0f : 0.0f;
#pragma unroll
            for (int i = 1; i < 10; ++i) {
                if (i > j) {
                    float s = 0.0f;
#pragma unroll
                    for (int m = 0; m < 10; ++m)
                        if (m >= j && m < i) s -= Rr[i * 10 + m] * Li[m][j];
                    Li[i][j] = s;
                }
            }
        }
        float Dl[10];
        float prod = 1.0f;
#pragma unroll
        for (int a = 0; a < 10; ++a) {
            float rd = Rr[a * 10 + a];
            float dv = rd * rd + 1e-4f;
            Dl[a] = 1.0f / dv;
            prod *= dv;
        }
        dets[t] = rsqrtf(prod);
#pragma unroll
        for (int i = 0; i < 10; ++i)
#pragma unroll
            for (int j = 0; j < 10; ++j) {
                float s = 0.0f;
#pragma unroll
                for (int a = 0; a < 10; ++a) s += Li[a][i] * Dl[a] * Li[a][j];
                Sinv[t * 100 + i * 10 + j] = s;
            }
    }
}

// ---------------------------------------------------------------------------
// Fused conv1(fp32) + conv2(MFMA f16) + bias/ReLU/2x2-maxpool.
// One block per image. B-fragments (all of conv2's weights: 144 VGPR/wave)
// are preloaded ONCE and PINNED via empty asm so the compiler can neither
// sink the loads into the loop (round-1 failure: 5.3 GB L2 re-reads) nor
// spill them (round-2 failure: 2.7 GB scratch traffic). ~200 VGPR -> 2
// waves/SIMD, which LDS-pipe analysis says is enough (floor ~26us).
// h2p layout: [b][co*144 + PY*12 + PX]
// ---------------------------------------------------------------------------
__global__ __launch_bounds__(256, 2) void k_convs(
    const float* __restrict__ x, const float* __restrict__ w1,
    const float* __restrict__ b1, const float* __restrict__ b2,
    const half_t* __restrict__ W2T, half_t* __restrict__ h2p) {
    __shared__ float s_x[784];
    __shared__ float s_w1[288];
    __shared__ float s_b1[32];
    __shared__ float s_b2[64];
    __shared__ __align__(16) half_t s_h1[4][26][26][8];  // [ci/8][y][x][ci%8]

    const int t = threadIdx.x;
    const int b = blockIdx.x;

    for (int i = t; i < 784; i += 256) s_x[i] = x[(size_t)b * 784 + i];
    for (int i = t; i < 288; i += 256) s_w1[i] = w1[i];
    if (t < 32) s_b1[t] = b1[t];
    if (t < 64) s_b2[t] = b2[t];
    __syncthreads();

    const int w = t >> 6;
    const int ln = t & 63;
    const int n16 = ln & 15;
    const int q = ln >> 4;

    // ---- conv1: wave g owns ci-group g (8 channels), lanes sweep 676 px ----
    {
        float wr[8][9], br[8];
#pragma unroll
        for (int j = 0; j < 8; ++j) {
            br[j] = s_b1[w * 8 + j];
#pragma unroll
            for (int k = 0; k < 9; ++k) wr[j][k] = s_w1[(w * 8 + j) * 9 + k];
        }
        for (int p = ln; p < 676; p += 64) {
            const int yy = p / 26;
            const int xx = p - yy * 26;
            float win[9];
#pragma unroll
            for (int r = 0; r < 3; ++r)
#pragma unroll
                for (int c = 0; c < 3; ++c) win[r * 3 + c] = s_x[(yy + r) * 28 + xx + c];
            half8 hv;
#pragma unroll
            for (int j = 0; j < 8; ++j) {
                float a = br[j];
#pragma unroll
                for (int k = 0; k < 9; ++k) a = fmaf(win[k], wr[j][k], a);
                hv[j] = (half_t)fmaxf(a, 0.0f);
            }
            *(half8*)(&s_h1[w][yy][xx][0]) = hv;
        }
    }

    // ---- preload ALL conv2 B-fragments (latency hides behind the barrier) --
    half8 bf[9][4];  // [tap][co-tile]: 144 VGPRs, pinned below
#pragma unroll
    for (int tap = 0; tap < 9; ++tap)
#pragma unroll
        for (int ct = 0; ct < 4; ++ct)
            bf[tap][ct] = *(const half8*)(W2T + ((tap * 64 + ct * 16 + n16) * 32 + q * 8));

    __syncthreads();

#pragma unroll
    for (int tap = 0; tap < 9; ++tap)
#pragma unroll
        for (int ct = 0; ct < 4; ++ct)
            asm volatile("" : "+v"(bf[tap][ct]));  // pin: no remat, no sink

    // ---- conv2: 36 M-tiles (12ty x 3tx of 2y x 8x), wave w owns 9 ----
    const int dy = (ln >> 3) & 1;  // A-row role: m = ln&15 -> (dy,dx)
    const int dx = ln & 7;

    for (int i = 0; i < 9; ++i) {
        const int mt = w * 9 + i;
        const int ty = mt / 3;       // pool row 0..11
        const int tx = mt - ty * 3;  // 0..2
        const int y0 = 2 * ty, x0 = 8 * tx;
        floatx4 acc[4];
#pragma unroll
        for (int ct = 0; ct < 4; ++ct) acc[ct] = (floatx4){0.f, 0.f, 0.f, 0.f};
#pragma unroll
        for (int tap = 0; tap < 9; ++tap) {
            const int ky = tap / 3;
            const int kx = tap - ky * 3;
            half8 af = *(const half8*)(&s_h1[q][y0 + dy + ky][x0 + dx + kx][0]);
#pragma unroll
            for (int ct = 0; ct < 4; ++ct) acc[ct] = MFMA16(af, bf[tap][ct], acc[ct]);
        }
        // 2x2 maxpool + bias + relu. C row m=q*4+reg; lane^32 is the dy partner.
#pragma unroll
        for (int ct = 0; ct < 4; ++ct) {
            float p0 = fmaxf(acc[ct][0], acc[ct][1]);
            float p1 = fmaxf(acc[ct][2], acc[ct][3]);
            p0 = fmaxf(p0, __shfl_xor(p0, 32, 64));
            p1 = fmaxf(p1, __shfl_xor(p1, 32, 64));
            if (q < 2) {
                const int co = ct * 16 + n16;
                const float bb = s_b2[co];
                half2v hz;
                hz[0] = (half_t)fmaxf(p0 + bb, 0.0f);
                hz[1] = (half_t)fmaxf(p1 + bb, 0.0f);
                *(half2v*)(h2p + (size_t)b * 9216 + co * 144 + ty * 12 + 4 * tx + 2 * q) = hz;
            }
        }
    }
}

// ---------------------------------------------------------------------------
// fc1: C[4096,128] = A[4096,9216](fp16) x W^T. Split-K=16 (chunk 576).
// LDS-free, barrier-free: fragments straight from global (A bytes read once
// grid-wide; W slice L2-hot). Grid 32x16 = 512 blocks. fp16 partials.
// ---------------------------------------------------------------------------
__global__ __launch_bounds__(256) void k_fc1(const half_t* __restrict__ A,
                                             const half_t* __restrict__ W,
                                             half_t* __restrict__ part) {
    const int t = threadIdx.x;
    const int mb = blockIdx.x;  // 0..31
    const int kb = blockIdx.y;  // 0..15
    const int w = t >> 6, ln = t & 63, n16 = ln & 15, q = ln >> 4;

    const half_t* a0 = A + (size_t)(mb * 128 + w * 32 + n16) * 9216 + kb * 576 + q * 8;
    const half_t* a1 = a0 + (size_t)16 * 9216;
    const half_t* wp = W + (size_t)n16 * 9216 + kb * 576 + q * 8;

    floatx4 acc[2][8];
#pragma unroll
    for (int s = 0; s < 2; ++s)
#pragma unroll
        for (int nt = 0; nt < 8; ++nt) acc[s][nt] = (floatx4){0.f, 0.f, 0.f, 0.f};

    for (int kt = 0; kt < 18; ++kt) {
        const int ko = kt * 32;
        half8 af0 = *(const half8*)(a0 + ko);
        half8 af1 = *(const half8*)(a1 + ko);
#pragma unroll
        for (int nt = 0; nt < 8; ++nt) {
            half8 bfr = *(const half8*)(wp + (size_t)nt * 16 * 9216 + ko);
            acc[0][nt] = MFMA16(af0, bfr, acc[0][nt]);
            acc[1][nt] = MFMA16(af1, bfr, acc[1][nt]);
        }
    }
    const int rowbase = mb * 128 + w * 32;
#pragma unroll
    for (int s = 0; s < 2; ++s)
#pragma unroll
        for (int nt = 0; nt < 8; ++nt)
#pragma unroll
            for (int r = 0; r < 4; ++r) {
                const int row = rowbase + s * 16 + q * 4 + r;
                const int col = nt * 16 + n16;
                part[(size_t)kb * 524288 + (size_t)row * 128 + col] = (half_t)acc[s][nt][r];
            }
}

// ---------------------------------------------------------------------------
// fc1 split-K reduction + bias + ReLU -> fp16 h3
// ---------------------------------------------------------------------------
__global__ void k_fc1red(const half_t* __restrict__ part, const float* __restrict__ b,
                         half_t* __restrict__ h3) {
    const int idx = blockIdx.x * 256 + threadIdx.x;  // 524288 exact
    const int col = idx & 127;
    float s = 0.0f;
#pragma unroll
    for (int j = 0; j < 16; ++j) s += (float)part[(size_t)j * 524288 + idx];
    s = fmaxf(s + b[col], 0.0f);
    h3[idx] = (half_t)s;
}

// ---------------------------------------------------------------------------
// fc2 + GMM posterior (fp32). One thread per sample.
// ---------------------------------------------------------------------------
__global__ __launch_bounds__(256) void k_fc2gmm(
    const half_t* __restrict__ h3, const float* __restrict__ fw,
    const float* __restrict__ fb, const float* __restrict__ cent,
    const float* __restrict__ Sinv, const float* __restrict__ dets,
    float* __restrict__ out) {
    __shared__ float sw[1280];
    __shared__ float sb[10];
    __shared__ float sc[100];
    __shared__ float ss[1000];
    __shared__ float sd[10];
    const int t = threadIdx.x;
    for (int i = t; i < 1280; i += 256) sw[i] = fw[i];
    if (t < 10) sb[t] = fb[t];
    if (t < 100) sc[t] = cent[t];
    for (int i = t; i < 1000; i += 256) ss[i] = Sinv[i];
    if (t < 10) sd[t] = dets[t];
    __syncthreads();

    const int bidx = blockIdx.x * 256 + t;  // 4096 samples exact
    half2v hh[64];
    const half2v* hp = (const half2v*)(h3 + (size_t)bidx * 128);
#pragma unroll
    for (int i = 0; i < 64; ++i) hh[i] = hp[i];

    float y[10];
#pragma unroll
    for (int o = 0; o < 10; ++o) {
        float a = sb[o];
#pragma unroll
        for (int k = 0; k < 64; ++k) {
            a = fmaf((float)hh[k][0], sw[o * 128 + 2 * k], a);
            a = fmaf((float)hh[k][1], sw[o * 128 + 2 * k + 1], a);
        }
        y[o] = a;
    }

    float expo[10];
    float mx = -3.402823466e38f;
#pragma unroll
    for (int k = 0; k < 10; ++k) {
        float d[10];
#pragma unroll
        for (int j = 0; j < 10; ++j) d[j] = y[j] - sc[k * 10 + j];
        float s = 0.0f;
#pragma unroll
        for (int i = 0; i < 10; ++i) {
            float r = 0.0f;
#pragma unroll
            for (int j = 0; j < 10; ++j) r = fmaf(ss[k * 100 + i * 10 + j], d[j], r);
            s = fmaf(d[i], r, s);
        }
        expo[k] = -0.5f * s;
        mx = fmaxf(mx, expo[k]);
    }
    float num[10];
    float sum = 0.0f;
#pragma unroll
    for (int k = 0; k < 10; ++k) {
        num[k] = sd[k] * __expf(expo[k] - mx);
        sum += num[k];
    }
    const float inv = 1.0f / sum;
#pragma unroll
    for (int k = 0; k < 10; ++k) out[(size_t)bidx * 10 + k] = num[k] * inv;
}

// ---------------------------------------------------------------------------
extern "C" void kernel_launch(void* const* d_in, const int* in_sizes, int n_in,
                              void* d_out, int out_size, void* d_ws, size_t ws_size,
                              hipStream_t stream) {
    const float* x = (const float*)d_in[0];
    const float* w1 = (const float*)d_in[1];
    const float* b1 = (const float*)d_in[2];
    const float* w2 = (const float*)d_in[3];
    const float* b2 = (const float*)d_in[4];
    const float* fw1 = (const float*)d_in[5];
    const float* fb1 = (const float*)d_in[6];
    const float* fw2 = (const float*)d_in[7];
    const float* fb2 = (const float*)d_in[8];
    const float* cen = (const float*)d_in[9];
    const float* raw = (const float*)d_in[10];
    float* out = (float*)d_out;

    char* ws = (char*)d_ws;
    half_t* W2T = (half_t*)(ws);                 //    36,864 B
    half_t* W1h = (half_t*)(ws + 36864);         // 2,359,296 B
    half_t* h2p = (half_t*)(ws + 2396160);       // 75,497,472 B
    half_t* part = (half_t*)(ws + 77893632);     // 16,777,216 B (16 x 524288 fp16)
    half_t* h3h = (half_t*)(ws + 94670848);      // 1,048,576 B
    float* gS = (float*)(ws + 95719424);         //     4,000 B
    float* gD = (float*)(ws + 95723424);         //        40 B  (total ~95.7 MB)

    k_prep<<<4681, 256, 0, stream>>>(fw1, W1h, w2, W2T, raw, gS, gD);
    k_convs<<<4096, 256, 0, stream>>>(x, w1, b1, b2, W2T, h2p);
    k_fc1<<<dim3(32, 16), 256, 0, stream>>>(h2p, W1h, part);
    k_fc1red<<<2048, 256, 0, stream>>>(part, fb1, h3h);
    k_fc2gmm<<<16, 256, 0, stream>>>(h3h, fw2, fb2, cen, gS, gD, out);
}